// Round 7
// baseline (273.890 us; speedup 1.0000x reference)
//
#include <hip/hip_runtime.h>

// Self-attention (B=8, N=4096, C=128) + residual + inference BatchNorm.
// R17: 8-wave flash blocks (512 thr), work split (key x q) = (4 x 2):
// wave (kw,qw) does S[keys kw*32..+32][q qw*32..+32] and PV[d kw*32..+32][same q].
// Rationale: R11/R16 reorders neutral, R14 barrier-cut won -> kernel is
// latency-bound at 2 waves/SIMD (tile 7.9Kcy vs ~4.2Kcy issue demand).
// This doubles waves/SIMD (2->4) at ~constant traffic (unlike R12 which
// doubled per-block memory): per-wave MFMA halves (16 S + 16 PV), 16 exp2.
//  - Kt 32KB single buffer, 8 DMA-eighths; eighths SHARED within qw-pair ->
//    safety: barrier A (lgkm) seals all kf reads before DMA issue; each wave
//    vmcnt(0)-drains its own DMA before barrier B => after B all K resident.
//  - single Pbuf 16KB; PV same-tile after barrier A. LDS 48KB -> 2 blocks/CU,
//    16 waves/CU.
//  - waves_per_eu(4,4): VGPR cap 128 for 4 waves/SIMD (working set ~125).
//
// ws: Wt 96KB | Qg 8M | Kg(swizzled) 8M | Vtg 8M  (~25.3 MB)

typedef __attribute__((ext_vector_type(8))) short bf16x8;
typedef __attribute__((ext_vector_type(4))) float f32x4;

__device__ __forceinline__ unsigned short f2bf(float f) {
  unsigned int u = __builtin_bit_cast(unsigned int, f);
  u += 0x7fffu + ((u >> 16) & 1u);   // RNE
  return (unsigned short)(u >> 16);
}
__device__ __forceinline__ unsigned int pack2(float a, float b) {
  return (unsigned int)f2bf(a) | ((unsigned int)f2bf(b) << 16);
}
// truncating pack via v_perm_b32: D = {b.hi16, a.hi16} in 1 VALU op
__device__ __forceinline__ unsigned int pack2t(float a, float b) {
  return __builtin_amdgcn_perm(__builtin_bit_cast(unsigned int, b),
                               __builtin_bit_cast(unsigned int, a),
                               0x07060302u);
}
// raw v_exp_f32 (args bounded: |s~| <~ 15, no guards needed)
__device__ __forceinline__ float fexp2(float x) {
  return __builtin_amdgcn_exp2f(x);
}

// async global->LDS DMA, 16B/lane: lds dest = uniform base + lane*16
__device__ __forceinline__ void dma16(const void* g, void* l) {
  __builtin_amdgcn_global_load_lds(
      (const __attribute__((address_space(1))) unsigned int*)g,
      (__attribute__((address_space(3))) unsigned int*)l, 16, 0, 0);
}

// 1/sqrt(128) * log2(e): softmax in exp2 domain; folded into Wq/bq.
#define SCALE_Q (0.08838834764831845f * 1.44269504088896340f)

// ---------------------------------------------------------------------------
// Kernel 1: W[k][n] fp32 -> Wt[n][k] bf16 (Wq pre-scaled). LDS-staged,
// coalesced loads (float4 linear) and stores (uint4, 16 lanes cover a row).
// ---------------------------------------------------------------------------
__global__ __launch_bounds__(256) void prep_wt(
    const float* __restrict__ wq, const float* __restrict__ wk,
    const float* __restrict__ wv, unsigned short* __restrict__ wt) {
  __shared__ float ws[128 * 129];   // padded: read bank spread
  const float* W = (blockIdx.x == 0) ? wq : (blockIdx.x == 1 ? wk : wv);
  const float sc = (blockIdx.x == 0) ? SCALE_Q : 1.0f;
  unsigned short* out = wt + blockIdx.x * 16384;
  const int t = threadIdx.x;

#pragma unroll
  for (int i = 0; i < 16; ++i) {
    int e = (i * 256 + t) * 4;          // linear float index, coalesced
    float4 v = *(const float4*)(W + e);
    int k = e >> 7, c = e & 127;
    float* d = ws + k * 129 + c;
    d[0] = v.x; d[1] = v.y; d[2] = v.z; d[3] = v.w;
  }
  __syncthreads();

  const int c = t & 15, n0 = t >> 4;   // 16 lanes cover one 256B output row
#pragma unroll
  for (int pass = 0; pass < 8; ++pass) {
    int n = pass * 16 + n0;
    const float* col = ws + n;
    unsigned int u0 = pack2(col[(c * 8 + 0) * 129] * sc, col[(c * 8 + 1) * 129] * sc);
    unsigned int u1 = pack2(col[(c * 8 + 2) * 129] * sc, col[(c * 8 + 3) * 129] * sc);
    unsigned int u2 = pack2(col[(c * 8 + 4) * 129] * sc, col[(c * 8 + 5) * 129] * sc);
    unsigned int u3 = pack2(col[(c * 8 + 6) * 129] * sc, col[(c * 8 + 7) * 129] * sc);
    *(uint4*)(out + n * 128 + c * 8) = make_uint4(u0, u1, u2, u3);
  }
}

// ---------------------------------------------------------------------------
// Kernel 2: fused QKV projection, grid(512). One x staging, three GEMMs with
// register-resident a-frags; obuf reused per-phase (barrier-separated).
// K stored pre-swizzled (chunk ^ row) with COALESCED stores (pos-major).
// ---------------------------------------------------------------------------
__global__ __launch_bounds__(256) void qkv_proj(
    const float* __restrict__ x, const unsigned short* __restrict__ wt,
    const float* __restrict__ bq, const float* __restrict__ bk, const float* __restrict__ bv,
    unsigned short* __restrict__ Qg, unsigned short* __restrict__ Kg,
    unsigned short* __restrict__ Vtg) {
  __shared__ unsigned short xs[64 * 128];    // swizzled bf16 x tile (16 KB)
  __shared__ unsigned short obuf[9216];      // bounce buffer (18 KB), reused x3
  const int t = threadIdx.x;
  const int rowblk = blockIdx.x * 64;

#pragma unroll
  for (int i = 0; i < 8; ++i) {
    int flat = t * 4 + i * 1024;
    int row = flat >> 7, col = flat & 127;
    float4 v = *(const float4*)(x + (size_t)(rowblk + row) * 128 + col);
    unsigned int u0 = pack2(v.x, v.y), u1 = pack2(v.z, v.w);
    int pos = (col >> 3) ^ (row & 15);
    *(uint2*)(xs + row * 128 + pos * 8 + (col & 7)) = make_uint2(u0, u1);
  }
  __syncthreads();

  const int lane = t & 63, wv_ = t >> 6;
  const int lm = lane & 15, quad = lane >> 4;

  bf16x8 a[4];
  {
    int row = wv_ * 16 + lm;
#pragma unroll
    for (int ks = 0; ks < 4; ++ks)
      a[ks] = __builtin_bit_cast(bf16x8,
          *(const uint4*)(xs + row * 128 + (((ks * 4 + quad) ^ lm) * 8)));
  }

  const int b   = rowblk >> 12;
  const int nb0 = rowblk & 4095;
  const f32x4 zero4 = {0.f, 0.f, 0.f, 0.f};

#pragma unroll
  for (int p = 0; p < 3; ++p) {
    const unsigned short* w = wt + p * 16384;
    const float* bias = (p == 0) ? bq : (p == 1 ? bk : bv);
    const float bsc = (p == 0) ? SCALE_Q : 1.0f;

    f32x4 acc[8];
#pragma unroll
    for (int ct = 0; ct < 8; ++ct) acc[ct] = zero4;

#pragma unroll
    for (int ct = 0; ct < 8; ++ct) {
      int n = ct * 16 + lm;
      const uint4* wp = (const uint4*)(w + n * 128 + quad * 8);
#pragma unroll
      for (int ks = 0; ks < 4; ++ks) {
        bf16x8 bfr = __builtin_bit_cast(bf16x8, wp[ks * 4]);
        acc[ct] = __builtin_amdgcn_mfma_f32_16x16x32_bf16(a[ks], bfr, acc[ct], 0, 0, 0);
      }
    }

    if (p < 2) {
      int rowb = wv_ * 16 + quad * 4;
#pragma unroll
      for (int ct = 0; ct < 8; ++ct) {
        int c = ct * 16 + lm;
        float bb = bias[c] * bsc;
#pragma unroll
        for (int r = 0; r < 4; ++r)
          obuf[(rowb + r) * 136 + c] = f2bf(acc[ct][r] + bb);
      }
      __syncthreads();
      unsigned short* og = (p == 0) ? Qg : Kg;
      int row = t >> 2;
#pragma unroll
      for (int j = 0; j < 4; ++j) {
        int pos = (t & 3) * 4 + j;                      // contiguous store pos
        int ch  = (p == 1) ? (pos ^ (row & 15)) : pos;  // LDS-side scatter
        uint4 vv = *(const uint4*)(obuf + row * 136 + ch * 8);
        *(uint4*)(og + (size_t)(rowblk + row) * 128 + pos * 8) = vv;
      }
      __syncthreads();   // obuf free for next phase
    } else {
      int key_base = wv_ * 16 + quad * 4;
#pragma unroll
      for (int ct = 0; ct < 8; ++ct) {
        int c = ct * 16 + lm;
        float bb = bias[c];
        unsigned int u0 = pack2(acc[ct][0] + bb, acc[ct][1] + bb);
        unsigned int u1 = pack2(acc[ct][2] + bb, acc[ct][3] + bb);
        *(uint2*)(obuf + c * 72 + key_base) = make_uint2(u0, u1);
      }
      __syncthreads();
      int d = t >> 1;
#pragma unroll
      for (int j = 0; j < 4; ++j) {
        int ch = (t & 1) * 4 + j;
        uint4 vv = *(const uint4*)(obuf + d * 72 + ch * 8);
        *(uint4*)(Vtg + (size_t)b * 524288 + (size_t)d * 4096 + nb0 + ch * 8) = vv;
      }
    }
  }
}

// ---------------------------------------------------------------------------
// Kernel 3: flash attention, 8 waves/block (512 thr), (key x q) = (4 x 2).
// grid(512) = 8b (XCD-local K/V) x 64 q-tiles of 64 rows.
// Per tile: V loads -> S (kf from LDS, qf regs) -> softmax -> [lgkm+barrier A]
// -> DMA K[t+1] (own eighth) -> PV (pf from LDS, vf regs) -> [lgkm+vmcnt(0)
// +barrier B]. After B all waves' K eighths are resident for tile t+1.
// ---------------------------------------------------------------------------
__global__ __launch_bounds__(512)
__attribute__((amdgpu_waves_per_eu(4, 4)))
void flash_attn(
    const unsigned short* __restrict__ Qg, const unsigned short* __restrict__ Kg,
    const unsigned short* __restrict__ Vtg, const float* __restrict__ x,
    const float* __restrict__ gamma, const float* __restrict__ beta,
    const float* __restrict__ mmean, const float* __restrict__ mvar,
    float* __restrict__ out) {
  __shared__ unsigned short Kt[16384];      // 32 KB, 8 DMA-eighths, swizzled rows
  __shared__ unsigned short Pbuf[8192];     // 16 KB (64 q x 128 key), single

  const int b  = blockIdx.x & 7;
  const int qt = blockIdx.x >> 3;          // 0..63
  const int t = threadIdx.x;
  const int lane = t & 63;
  const int w = t >> 6;                    // 0..7
  const int kw = w >> 1, qw = w & 1;       // key-quarter, q-half
  const int lm = lane & 15, quad = lane >> 4;
  const int q0 = qt * 64;

  const unsigned short* Qb = Qg  + (size_t)b * 524288;
  const unsigned short* Kb = Kg  + (size_t)b * 524288;
  const unsigned short* Vb = Vtg + (size_t)b * 524288;

  // K[0] DMA FIRST (4 reqs, oldest vmcnt entries); own eighth = keys w*16..+16
  {
    const unsigned short* src = Kb + (size_t)w * 2048 + lane * 8;
    unsigned short* dst = &Kt[w * 2048];
#pragma unroll
    for (int j = 0; j < 4; ++j) dma16(src + j * 512, dst + j * 512);
  }

  // Q as B-fragments (k=d, n=q), register-resident (pre-scaled); own q-half
  bf16x8 qf[2][4];
#pragma unroll
  for (int nt = 0; nt < 2; ++nt) {
    const uint4* qp = (const uint4*)(Qb + (size_t)(q0 + qw * 32 + nt * 16 + lm) * 128 + quad * 8);
#pragma unroll
    for (int ks = 0; ks < 4; ++ks) qf[nt][ks] = __builtin_bit_cast(bf16x8, qp[ks * 4]);
  }

  // drain own K[0] DMA (4 oldest of 4+8 outstanding) then sync all waves
  asm volatile("s_waitcnt vmcnt(8)" ::: "memory");
  __builtin_amdgcn_s_barrier();

  const f32x4 zero4 = {0.f, 0.f, 0.f, 0.f};
  f32x4 o[2][2];
#pragma unroll
  for (int mt = 0; mt < 2; ++mt)
#pragma unroll
    for (int nt = 0; nt < 2; ++nt) o[mt][nt] = zero4;
  float lp[2] = {0.f, 0.f};

#pragma unroll 1
  for (int kt = 0; kt < 32; ++kt) {
    const int key0 = kt * 128;

    // V^T rows (wave's 32 d) register-direct; consumed by PV this tile
    // (window = S + softmax + barrier A)
    bf16x8 vf[2][4];
#pragma unroll
    for (int mt = 0; mt < 2; ++mt) {
      const uint4* vp = (const uint4*)(Vb + (size_t)(kw * 32 + mt * 16 + lm) * 4096 + key0 + quad * 8);
#pragma unroll
      for (int ks = 0; ks < 4; ++ks) vf[mt][ks] = __builtin_bit_cast(bf16x8, vp[ks * 4]);
    }

    // S^T = K * Q^T: keys kw*32..+32 (LDS, swizzled chunks) x q qw*32..+32
    f32x4 sa[2][2];
#pragma unroll
    for (int mt = 0; mt < 2; ++mt)
#pragma unroll
      for (int nt = 0; nt < 2; ++nt) sa[mt][nt] = zero4;
#pragma unroll
    for (int mt = 0; mt < 2; ++mt) {
      const unsigned short* kr = &Kt[(kw * 32 + mt * 16 + lm) * 128];
      bf16x8 kf[4];
#pragma unroll
      for (int ks = 0; ks < 4; ++ks)
        kf[ks] = __builtin_bit_cast(bf16x8, *(const uint4*)(kr + ((ks * 4 + quad) ^ lm) * 8));
#pragma unroll
      for (int ks = 0; ks < 4; ++ks)
#pragma unroll
        for (int nt = 0; nt < 2; ++nt)
          sa[mt][nt] = __builtin_amdgcn_mfma_f32_16x16x32_bf16(kf[ks], qf[nt][ks], sa[mt][nt], 0, 0, 0);
    }

    // softmax: P = exp2(S~) -> Pbuf rows q = qw*32+nt*16+lm, chunks c16^lm
    {
      const int sub = (quad & 1) * 4;
#pragma unroll
      for (int mt = 0; mt < 2; ++mt) {
        int c16 = kw * 4 + mt * 2 + (quad >> 1);
        int pos = c16 ^ lm;
#pragma unroll
        for (int nt = 0; nt < 2; ++nt) {
          float e0 = fexp2(sa[mt][nt][0]), e1 = fexp2(sa[mt][nt][1]);
          float e2 = fexp2(sa[mt][nt][2]), e3 = fexp2(sa[mt][nt][3]);
          lp[nt] += (e0 + e1) + (e2 + e3);
          *(uint2*)(Pbuf + (qw * 32 + nt * 16 + lm) * 128 + pos * 8 + sub) =
              make_uint2(pack2t(e0, e1), pack2t(e2, e3));
        }
      }
    }

    // barrier A: ALL waves' kf reads retired (K overwrite safe) + P visible.
    // lgkm-only: V loads stay in flight.
    asm volatile("s_waitcnt lgkmcnt(0)\n\ts_barrier" ::: "memory");

    // DMA K[t+1] into own eighth (deadline: barrier B via own vmcnt(0))
    if (kt + 1 < 32) {
      const unsigned short* src = Kb + (size_t)(kt + 1) * 16384 + w * 2048 + lane * 8;
      unsigned short* dst = &Kt[w * 2048];
#pragma unroll
      for (int j = 0; j < 4; ++j) dma16(src + j * 512, dst + j * 512);
    }

    // PV: O^T += V^T * P^T (pf from LDS all 128 keys x own q; vf wait is
    // compiler-counted vmcnt(4), leaves the 4 DMA reqs in flight)
    {
      const uint4* Pr = (const uint4*)Pbuf;
#pragma unroll
      for (int nt = 0; nt < 2; ++nt) {
        bf16x8 pf[4];
#pragma unroll
        for (int ks = 0; ks < 4; ++ks)
          pf[ks] = __builtin_bit_cast(bf16x8, Pr[(qw * 32 + nt * 16 + lm) * 16 + ((ks * 4 + quad) ^ lm)]);
#pragma unroll
        for (int ks = 0; ks < 4; ++ks)
#pragma unroll
          for (int mt = 0; mt < 2; ++mt)
            o[mt][nt] = __builtin_amdgcn_mfma_f32_16x16x32_bf16(vf[mt][ks], pf[ks], o[mt][nt], 0, 0, 0);
      }
    }

    // barrier B: pf reads retired (Pbuf WAR) + own DMA drained -> after B,
    // every wave's K[t+1] eighth is resident for all readers.
    asm volatile("s_waitcnt vmcnt(0) lgkmcnt(0)\n\ts_barrier" ::: "memory");
  }

  // l reduction: quads (keys within wave) via shfl, then across kw via Pbuf
  float* lred = (float*)Pbuf;
#pragma unroll
  for (int nt = 0; nt < 2; ++nt) {
    lp[nt] += __shfl_xor(lp[nt], 16);
    lp[nt] += __shfl_xor(lp[nt], 32);
  }
  if (quad == 0) {
#pragma unroll
    for (int nt = 0; nt < 2; ++nt)
      lred[kw * 64 + qw * 32 + nt * 16 + lm] = lp[nt];
  }
  __syncthreads();
  float rl[2];
#pragma unroll
  for (int nt = 0; nt < 2; ++nt) {
    int q = qw * 32 + nt * 16 + lm;
    rl[nt] = 1.0f / ((lred[q] + lred[64 + q]) + (lred[128 + q] + lred[192 + q]));
  }

  // epilogue: lane holds 4 consecutive d at fixed q -> float4 stores
#pragma unroll
  for (int mt = 0; mt < 2; ++mt) {
    int c0 = kw * 32 + mt * 16 + quad * 4;
    float4 gm = *(const float4*)(gamma + c0);
    float4 bt = *(const float4*)(beta + c0);
    float4 mm = *(const float4*)(mmean + c0);
    float4 mv = *(const float4*)(mvar + c0);
    float iv0 = gm.x * rsqrtf(mv.x + 1e-3f), iv1 = gm.y * rsqrtf(mv.y + 1e-3f);
    float iv2 = gm.z * rsqrtf(mv.z + 1e-3f), iv3 = gm.w * rsqrtf(mv.w + 1e-3f);
    float ad0 = bt.x - mm.x * iv0, ad1 = bt.y - mm.y * iv1;
    float ad2 = bt.z - mm.z * iv2, ad3 = bt.w - mm.w * iv3;
#pragma unroll
    for (int nt = 0; nt < 2; ++nt) {
      size_t g = ((size_t)b * 4096 + q0 + qw * 32 + nt * 16 + lm) * 128 + c0;
      float4 xr = *(const float4*)(x + g);
      float4 ov;
      ov.x = (o[mt][nt][0] * rl[nt] + xr.x) * iv0 + ad0;
      ov.y = (o[mt][nt][1] * rl[nt] + xr.y) * iv1 + ad1;
      ov.z = (o[mt][nt][2] * rl[nt] + xr.z) * iv2 + ad2;
      ov.w = (o[mt][nt][3] * rl[nt] + xr.w) * iv3 + ad3;
      *(float4*)(out + g) = ov;
    }
  }
}

// ---------------------------------------------------------------------------
extern "C" void kernel_launch(void* const* d_in, const int* in_sizes, int n_in,
                              void* d_out, int out_size, void* d_ws, size_t ws_size,
                              hipStream_t stream) {
  const float* x     = (const float*)d_in[0];
  const float* wq    = (const float*)d_in[1];
  const float* bq    = (const float*)d_in[2];
  const float* wk    = (const float*)d_in[3];
  const float* bk    = (const float*)d_in[4];
  const float* wv    = (const float*)d_in[5];
  const float* bv    = (const float*)d_in[6];
  const float* gamma = (const float*)d_in[7];
  const float* beta  = (const float*)d_in[8];
  const float* mmean = (const float*)d_in[9];
  const float* mvar  = (const float*)d_in[10];
  float* out = (float*)d_out;

  unsigned short* wt  = (unsigned short*)d_ws;
  unsigned short* Qg  = wt + 3 * 128 * 128;
  unsigned short* Kg  = Qg + 8 * 4096 * 128;     // pre-swizzled rows
  unsigned short* Vtg = Kg + 8 * 4096 * 128;

  prep_wt<<<dim3(3), dim3(256), 0, stream>>>(wq, wk, wv, wt);
  qkv_proj<<<dim3(512), dim3(256), 0, stream>>>(x, wt, bq, bk, bv, Qg, Kg, Vtg);
  flash_attn<<<dim3(512), dim3(512), 0, stream>>>(Qg, Kg, Vtg, x, gamma, beta,
                                                  mmean, mvar, out);
}

// Round 8
// 207.347 us; speedup vs baseline: 1.3209x; 1.3209x over previous
//
#include <hip/hip_runtime.h>

// Self-attention (B=8, N=4096, C=128) + residual + inference BatchNorm.
// R18: KVBLK 128 -> 64. Cycle model from R17's counters: MfmaUtil 28% ==
// 2 waves/SIMD x 64 MFMA x 19.4cy / 7.66Kcy-tile; the pipe idles because LDS
// (64KB -> 2 blocks/CU) caps TLP, and VGPR-squeeze attempts (R12/13/17) are
// fatal. Halving the KV tile halves LDS to 32KB (Kt 16KB + 2x8KB Pbuf) ->
// 4 blocks/CU at the compiler's NATURAL ~100 VGPR (no waves_per_eu attr --
// three rounds proved min-waves hints squeeze to 64 VGPR and lose 65%).
// Per-block traffic is UNCHANGED (R12's doubling mistake avoided): per-wave
// per-tile work halves, tile count doubles. R14's 1-barrier pipelined
// structure kept verbatim: S[t] -> softmax[t]->Pbuf[t&1] -> DMA K[t+1] ->
// PV[t-1] -> V[t] loads -> lgkm+barrier.
//
// ws: Wt 96KB | Qg 8M | Kg(swizzled) 8M | Vtg 8M  (~25.3 MB)

typedef __attribute__((ext_vector_type(8))) short bf16x8;
typedef __attribute__((ext_vector_type(4))) float f32x4;

__device__ __forceinline__ unsigned short f2bf(float f) {
  unsigned int u = __builtin_bit_cast(unsigned int, f);
  u += 0x7fffu + ((u >> 16) & 1u);   // RNE
  return (unsigned short)(u >> 16);
}
__device__ __forceinline__ unsigned int pack2(float a, float b) {
  return (unsigned int)f2bf(a) | ((unsigned int)f2bf(b) << 16);
}
// truncating pack via v_perm_b32: D = {b.hi16, a.hi16} in 1 VALU op
__device__ __forceinline__ unsigned int pack2t(float a, float b) {
  return __builtin_amdgcn_perm(__builtin_bit_cast(unsigned int, b),
                               __builtin_bit_cast(unsigned int, a),
                               0x07060302u);
}
// raw v_exp_f32 (args bounded: |s~| <~ 15, no guards needed)
__device__ __forceinline__ float fexp2(float x) {
  return __builtin_amdgcn_exp2f(x);
}

// async global->LDS DMA, 16B/lane: lds dest = uniform base + lane*16
__device__ __forceinline__ void dma16(const void* g, void* l) {
  __builtin_amdgcn_global_load_lds(
      (const __attribute__((address_space(1))) unsigned int*)g,
      (__attribute__((address_space(3))) unsigned int*)l, 16, 0, 0);
}

// 1/sqrt(128) * log2(e): softmax in exp2 domain; folded into Wq/bq.
#define SCALE_Q (0.08838834764831845f * 1.44269504088896340f)

// ---------------------------------------------------------------------------
// Kernel 1: W[k][n] fp32 -> Wt[n][k] bf16 (Wq pre-scaled). LDS-staged,
// coalesced loads (float4 linear) and stores (uint4, 16 lanes cover a row).
// ---------------------------------------------------------------------------
__global__ __launch_bounds__(256) void prep_wt(
    const float* __restrict__ wq, const float* __restrict__ wk,
    const float* __restrict__ wv, unsigned short* __restrict__ wt) {
  __shared__ float ws[128 * 129];   // padded: read bank spread
  const float* W = (blockIdx.x == 0) ? wq : (blockIdx.x == 1 ? wk : wv);
  const float sc = (blockIdx.x == 0) ? SCALE_Q : 1.0f;
  unsigned short* out = wt + blockIdx.x * 16384;
  const int t = threadIdx.x;

#pragma unroll
  for (int i = 0; i < 16; ++i) {
    int e = (i * 256 + t) * 4;          // linear float index, coalesced
    float4 v = *(const float4*)(W + e);
    int k = e >> 7, c = e & 127;
    float* d = ws + k * 129 + c;
    d[0] = v.x; d[1] = v.y; d[2] = v.z; d[3] = v.w;
  }
  __syncthreads();

  const int c = t & 15, n0 = t >> 4;   // 16 lanes cover one 256B output row
#pragma unroll
  for (int pass = 0; pass < 8; ++pass) {
    int n = pass * 16 + n0;
    const float* col = ws + n;
    unsigned int u0 = pack2(col[(c * 8 + 0) * 129] * sc, col[(c * 8 + 1) * 129] * sc);
    unsigned int u1 = pack2(col[(c * 8 + 2) * 129] * sc, col[(c * 8 + 3) * 129] * sc);
    unsigned int u2 = pack2(col[(c * 8 + 4) * 129] * sc, col[(c * 8 + 5) * 129] * sc);
    unsigned int u3 = pack2(col[(c * 8 + 6) * 129] * sc, col[(c * 8 + 7) * 129] * sc);
    *(uint4*)(out + n * 128 + c * 8) = make_uint4(u0, u1, u2, u3);
  }
}

// ---------------------------------------------------------------------------
// Kernel 2: fused QKV projection, grid(512). One x staging, three GEMMs with
// register-resident a-frags; obuf reused per-phase (barrier-separated).
// K stored pre-swizzled (chunk ^ row) with COALESCED stores (pos-major).
// ---------------------------------------------------------------------------
__global__ __launch_bounds__(256) void qkv_proj(
    const float* __restrict__ x, const unsigned short* __restrict__ wt,
    const float* __restrict__ bq, const float* __restrict__ bk, const float* __restrict__ bv,
    unsigned short* __restrict__ Qg, unsigned short* __restrict__ Kg,
    unsigned short* __restrict__ Vtg) {
  __shared__ unsigned short xs[64 * 128];    // swizzled bf16 x tile (16 KB)
  __shared__ unsigned short obuf[9216];      // bounce buffer (18 KB), reused x3
  const int t = threadIdx.x;
  const int rowblk = blockIdx.x * 64;

#pragma unroll
  for (int i = 0; i < 8; ++i) {
    int flat = t * 4 + i * 1024;
    int row = flat >> 7, col = flat & 127;
    float4 v = *(const float4*)(x + (size_t)(rowblk + row) * 128 + col);
    unsigned int u0 = pack2(v.x, v.y), u1 = pack2(v.z, v.w);
    int pos = (col >> 3) ^ (row & 15);
    *(uint2*)(xs + row * 128 + pos * 8 + (col & 7)) = make_uint2(u0, u1);
  }
  __syncthreads();

  const int lane = t & 63, wv_ = t >> 6;
  const int lm = lane & 15, quad = lane >> 4;

  bf16x8 a[4];
  {
    int row = wv_ * 16 + lm;
#pragma unroll
    for (int ks = 0; ks < 4; ++ks)
      a[ks] = __builtin_bit_cast(bf16x8,
          *(const uint4*)(xs + row * 128 + (((ks * 4 + quad) ^ lm) * 8)));
  }

  const int b   = rowblk >> 12;
  const int nb0 = rowblk & 4095;
  const f32x4 zero4 = {0.f, 0.f, 0.f, 0.f};

#pragma unroll
  for (int p = 0; p < 3; ++p) {
    const unsigned short* w = wt + p * 16384;
    const float* bias = (p == 0) ? bq : (p == 1 ? bk : bv);
    const float bsc = (p == 0) ? SCALE_Q : 1.0f;

    f32x4 acc[8];
#pragma unroll
    for (int ct = 0; ct < 8; ++ct) acc[ct] = zero4;

#pragma unroll
    for (int ct = 0; ct < 8; ++ct) {
      int n = ct * 16 + lm;
      const uint4* wp = (const uint4*)(w + n * 128 + quad * 8);
#pragma unroll
      for (int ks = 0; ks < 4; ++ks) {
        bf16x8 bfr = __builtin_bit_cast(bf16x8, wp[ks * 4]);
        acc[ct] = __builtin_amdgcn_mfma_f32_16x16x32_bf16(a[ks], bfr, acc[ct], 0, 0, 0);
      }
    }

    if (p < 2) {
      int rowb = wv_ * 16 + quad * 4;
#pragma unroll
      for (int ct = 0; ct < 8; ++ct) {
        int c = ct * 16 + lm;
        float bb = bias[c] * bsc;
#pragma unroll
        for (int r = 0; r < 4; ++r)
          obuf[(rowb + r) * 136 + c] = f2bf(acc[ct][r] + bb);
      }
      __syncthreads();
      unsigned short* og = (p == 0) ? Qg : Kg;
      int row = t >> 2;
#pragma unroll
      for (int j = 0; j < 4; ++j) {
        int pos = (t & 3) * 4 + j;                      // contiguous store pos
        int ch  = (p == 1) ? (pos ^ (row & 15)) : pos;  // LDS-side scatter
        uint4 vv = *(const uint4*)(obuf + row * 136 + ch * 8);
        *(uint4*)(og + (size_t)(rowblk + row) * 128 + pos * 8) = vv;
      }
      __syncthreads();   // obuf free for next phase
    } else {
      int key_base = wv_ * 16 + quad * 4;
#pragma unroll
      for (int ct = 0; ct < 8; ++ct) {
        int c = ct * 16 + lm;
        float bb = bias[c];
        unsigned int u0 = pack2(acc[ct][0] + bb, acc[ct][1] + bb);
        unsigned int u1 = pack2(acc[ct][2] + bb, acc[ct][3] + bb);
        *(uint2*)(obuf + c * 72 + key_base) = make_uint2(u0, u1);
      }
      __syncthreads();
      int d = t >> 1;
#pragma unroll
      for (int j = 0; j < 4; ++j) {
        int ch = (t & 1) * 4 + j;
        uint4 vv = *(const uint4*)(obuf + d * 72 + ch * 8);
        *(uint4*)(Vtg + (size_t)b * 524288 + (size_t)d * 4096 + nb0 + ch * 8) = vv;
      }
    }
  }
}

// ---------------------------------------------------------------------------
// Kernel 3: flash attention, KVBLK=64, PV pipelined one tile back, 1 barrier
// per tile. grid(512) = 8b x 64 q-tiles of 64 rows; 256 thr = 4 waves.
// LDS 32KB (Kt 16KB wave-private quarters + 2x8KB Pbuf) -> 4 blocks/CU at
// natural VGPR (~100). Per tile (64 total): vmcnt(4) [own K DMA] -> S (16
// MFMA) -> softmax (16 exp2) -> lgkm, DMA K[t+1] (4 reqs) -> PV[t-1] (16
// MFMA) -> V[t] loads (4) -> lgkm+barrier.
// ---------------------------------------------------------------------------
__global__ __launch_bounds__(256)
void flash_attn(
    const unsigned short* __restrict__ Qg, const unsigned short* __restrict__ Kg,
    const unsigned short* __restrict__ Vtg, const float* __restrict__ x,
    const float* __restrict__ gamma, const float* __restrict__ beta,
    const float* __restrict__ mmean, const float* __restrict__ mvar,
    float* __restrict__ out) {
  __shared__ unsigned short Kt[8192];        // 16 KB, wave-private 4KB quarters
  __shared__ unsigned short Pbuf[2][4096];   // 2 x 8 KB (64 q x 64 key)

  const int b  = blockIdx.x & 7;
  const int qt = blockIdx.x >> 3;          // 0..63
  const int t = threadIdx.x;
  const int lane = t & 63;
  const int w = t >> 6;                    // 0..3
  const int lm = lane & 15, quad = lane >> 4;
  const int q0 = qt * 64;

  const unsigned short* Qb = Qg  + (size_t)b * 524288;
  const unsigned short* Kb = Kg  + (size_t)b * 524288;
  const unsigned short* Vb = Vtg + (size_t)b * 524288;

  // K[0] DMA FIRST (4 reqs, oldest vmcnt entries). Wave quarter = keys w*16..+16.
  {
    const unsigned short* src = Kb + (size_t)w * 2048 + lane * 8;
    unsigned short* dst = &Kt[w * 2048];
#pragma unroll
    for (int j = 0; j < 4; ++j) dma16(src + j * 512, dst + j * 512);
  }

  // Q as B-fragments (k=d, n=q), register-resident (pre-scaled), all 64 q
  bf16x8 qf[4][4];
#pragma unroll
  for (int nt = 0; nt < 4; ++nt) {
    const uint4* qp = (const uint4*)(Qb + (size_t)(q0 + nt * 16 + lm) * 128 + quad * 8);
#pragma unroll
    for (int ks = 0; ks < 4; ++ks) qf[nt][ks] = __builtin_bit_cast(bf16x8, qp[ks * 4]);
  }

  const f32x4 zero4 = {0.f, 0.f, 0.f, 0.f};
  f32x4 o[2][4];
#pragma unroll
  for (int mt = 0; mt < 2; ++mt)
#pragma unroll
    for (int nt = 0; nt < 4; ++nt) o[mt][nt] = zero4;
  float lp[4] = {0.f, 0.f, 0.f, 0.f};
  bf16x8 vf[2][2];   // V[t] regs (32d x 64 keys); consumed by PV[t] next iter

#pragma unroll 1
  for (int kt = 0; kt < 64; ++kt) {
    const int key0 = kt * 64;

    // own K[kt] DMA (4 oldest vmem entries) landed; V[kt-1] (4 newer) and the
    // qf tail at kt=0 may stay in flight.
    asm volatile("s_waitcnt vmcnt(4)" ::: "memory");

    // S^T = K * Q^T: own 16 keys (LDS, swizzled chunks) x all 64 q. 16 MFMAs.
    f32x4 sa[4];
#pragma unroll
    for (int nt = 0; nt < 4; ++nt) sa[nt] = zero4;
    {
      const unsigned short* kr = &Kt[(w * 16 + lm) * 128];
      bf16x8 kf[4];
#pragma unroll
      for (int ks = 0; ks < 4; ++ks)
        kf[ks] = __builtin_bit_cast(bf16x8, *(const uint4*)(kr + ((ks * 4 + quad) ^ lm) * 8));
#pragma unroll
      for (int ks = 0; ks < 4; ++ks)
#pragma unroll
        for (int nt = 0; nt < 4; ++nt)
          sa[nt] = __builtin_amdgcn_mfma_f32_16x16x32_bf16(kf[ks], qf[nt][ks], sa[nt], 0, 0, 0);
    }

    // softmax[kt] -> Pbuf[kt&1]: keys w*16+quad*4+r, q = nt*16+lm.
    // chunk c8 = w*2+(quad>>1) of 8; row-swizzle pos = c8 ^ (q&7).
    {
      unsigned short* Ps = Pbuf[kt & 1];
      const int c8 = w * 2 + (quad >> 1);
      const int sub = (quad & 1) * 4;
#pragma unroll
      for (int nt = 0; nt < 4; ++nt) {
        float e0 = fexp2(sa[nt][0]), e1 = fexp2(sa[nt][1]);
        float e2 = fexp2(sa[nt][2]), e3 = fexp2(sa[nt][3]);
        lp[nt] += (e0 + e1) + (e2 + e3);
        int pos = c8 ^ (lm & 7);
        *(uint2*)(Ps + (nt * 16 + lm) * 64 + pos * 8 + sub) =
            make_uint2(pack2t(e0, e1), pack2t(e2, e3));
      }
    }

    // own kf reads retired -> overwrite own quarter; DMA K[kt+1] (4 reqs)
    asm volatile("s_waitcnt lgkmcnt(0)" ::: "memory");
    if (kt + 1 < 64) {
      const unsigned short* src = Kb + (size_t)(kt + 1) * 8192 + w * 2048 + lane * 8;
      unsigned short* dst = &Kt[w * 2048];
#pragma unroll
      for (int j = 0; j < 4; ++j) dma16(src + j * 512, dst + j * 512);
    }

    // PV[kt-1]: O^T += V^T[kt-1] * P^T[kt-1] (Pbuf[(kt-1)&1], vf regs).
    // vf wait is compiler-counted (4 DMA newer -> vmcnt(4)), DMA stays live.
    if (kt > 0) {
      const uint4* Pr = (const uint4*)Pbuf[(kt & 1) ^ 1];
#pragma unroll
      for (int nt = 0; nt < 4; ++nt) {
        bf16x8 pf[2];
#pragma unroll
        for (int ks = 0; ks < 2; ++ks)
          pf[ks] = __builtin_bit_cast(bf16x8, Pr[(nt * 16 + lm) * 8 + ((ks * 4 + quad) ^ (lm & 7))]);
#pragma unroll
        for (int ks = 0; ks < 2; ++ks)
#pragma unroll
          for (int mt = 0; mt < 2; ++mt)
            o[mt][nt] = __builtin_amdgcn_mfma_f32_16x16x32_bf16(vf[mt][ks], pf[ks], o[mt][nt], 0, 0, 0);
      }
    }

    // V[kt] loads -> vf (consumed next iter; window = barrier + S + softmax)
#pragma unroll
    for (int mt = 0; mt < 2; ++mt) {
      const uint4* vp = (const uint4*)(Vb + (size_t)(w * 32 + mt * 16 + lm) * 4096 + key0 + quad * 8);
#pragma unroll
      for (int ks = 0; ks < 2; ++ks) vf[mt][ks] = __builtin_bit_cast(bf16x8, vp[ks * 4]);
    }

    // single barrier: P[kt] visible; all pf reads of Pbuf[(kt-1)&1] retired
    // (lgkm only -- V loads + K DMA stay in flight)
    asm volatile("s_waitcnt lgkmcnt(0)\n\ts_barrier" ::: "memory");
  }

  // epilogue: PV[63] (Pbuf[1], vf = V[63]; compiler waits the V loads)
  {
    const uint4* Pr = (const uint4*)Pbuf[1];
#pragma unroll
    for (int nt = 0; nt < 4; ++nt) {
      bf16x8 pf[2];
#pragma unroll
      for (int ks = 0; ks < 2; ++ks)
        pf[ks] = __builtin_bit_cast(bf16x8, Pr[(nt * 16 + lm) * 8 + ((ks * 4 + quad) ^ (lm & 7))]);
#pragma unroll
      for (int ks = 0; ks < 2; ++ks)
#pragma unroll
        for (int mt = 0; mt < 2; ++mt)
          o[mt][nt] = __builtin_amdgcn_mfma_f32_16x16x32_bf16(vf[mt][ks], pf[ks], o[mt][nt], 0, 0, 0);
    }
  }

  // l reduction: quads (keys) in-wave via shfl, then across waves via Pbuf[0]
  // floats (disjoint from Pbuf[1] still read by other waves' epilogue PV)
  float* lred = (float*)Pbuf[0];
#pragma unroll
  for (int nt = 0; nt < 4; ++nt) {
    lp[nt] += __shfl_xor(lp[nt], 16);
    lp[nt] += __shfl_xor(lp[nt], 32);
  }
  if (quad == 0) {
#pragma unroll
    for (int nt = 0; nt < 4; ++nt) lred[w * 64 + nt * 16 + lm] = lp[nt];
  }
  __syncthreads();
  float rl[4];
#pragma unroll
  for (int nt = 0; nt < 4; ++nt) {
    int q = nt * 16 + lm;
    rl[nt] = 1.0f / ((lred[q] + lred[64 + q]) + (lred[128 + q] + lred[192 + q]));
  }

  // epilogue: lane holds 4 consecutive d at fixed q -> float4 stores
#pragma unroll
  for (int mt = 0; mt < 2; ++mt) {
    int c0 = w * 32 + mt * 16 + quad * 4;
    float4 gm = *(const float4*)(gamma + c0);
    float4 bt = *(const float4*)(beta + c0);
    float4 mm = *(const float4*)(mmean + c0);
    float4 mv = *(const float4*)(mvar + c0);
    float iv0 = gm.x * rsqrtf(mv.x + 1e-3f), iv1 = gm.y * rsqrtf(mv.y + 1e-3f);
    float iv2 = gm.z * rsqrtf(mv.z + 1e-3f), iv3 = gm.w * rsqrtf(mv.w + 1e-3f);
    float ad0 = bt.x - mm.x * iv0, ad1 = bt.y - mm.y * iv1;
    float ad2 = bt.z - mm.z * iv2, ad3 = bt.w - mm.w * iv3;
#pragma unroll
    for (int nt = 0; nt < 4; ++nt) {
      size_t g = ((size_t)b * 4096 + q0 + nt * 16 + lm) * 128 + c0;
      float4 xr = *(const float4*)(x + g);
      float4 ov;
      ov.x = (o[mt][nt][0] * rl[nt] + xr.x) * iv0 + ad0;
      ov.y = (o[mt][nt][1] * rl[nt] + xr.y) * iv1 + ad1;
      ov.z = (o[mt][nt][2] * rl[nt] + xr.z) * iv2 + ad2;
      ov.w = (o[mt][nt][3] * rl[nt] + xr.w) * iv3 + ad3;
      *(float4*)(out + g) = ov;
    }
  }
}

// ---------------------------------------------------------------------------
extern "C" void kernel_launch(void* const* d_in, const int* in_sizes, int n_in,
                              void* d_out, int out_size, void* d_ws, size_t ws_size,
                              hipStream_t stream) {
  const float* x     = (const float*)d_in[0];
  const float* wq    = (const float*)d_in[1];
  const float* bq    = (const float*)d_in[2];
  const float* wk    = (const float*)d_in[3];
  const float* bk    = (const float*)d_in[4];
  const float* wv    = (const float*)d_in[5];
  const float* bv    = (const float*)d_in[6];
  const float* gamma = (const float*)d_in[7];
  const float* beta  = (const float*)d_in[8];
  const float* mmean = (const float*)d_in[9];
  const float* mvar  = (const float*)d_in[10];
  float* out = (float*)d_out;

  unsigned short* wt  = (unsigned short*)d_ws;
  unsigned short* Qg  = wt + 3 * 128 * 128;
  unsigned short* Kg  = Qg + 8 * 4096 * 128;     // pre-swizzled rows
  unsigned short* Vtg = Kg + 8 * 4096 * 128;

  prep_wt<<<dim3(3), dim3(256), 0, stream>>>(wq, wk, wv, wt);
  qkv_proj<<<dim3(512), dim3(256), 0, stream>>>(x, wt, bq, bk, bv, Qg, Kg, Vtg);
  flash_attn<<<dim3(512), dim3(256), 0, stream>>>(Qg, Kg, Vtg, x, gamma, beta,
                                                  mmean, mvar, out);
}